// Round 3
// baseline (62.987 us; speedup 1.0000x reference)
//
#include <hip/hip_runtime.h>

// ---- problem constants ----
#define B_TOK   128
#define E_TOP   4
#define NEXP    32
#define KDIM    512
#define CDIM    1024
#define PAIRS   (B_TOK * E_TOP)   // 512
#define HALF_C  (CDIM / 2)        // 512

#define ALPHA   1.702f
#define LIMIT   7.0f

// ---- tiling ----
#define CH      64                // channels per block (16 c-chunks)
#define TT      16                // tokens per work item
#define MAXIT   64                // max schedule items (Σceil(Te/16) ≤ 32+32)

// =====================================================================
// Kernel 1: bucket (b,e) pairs by expert AND build the work-item
// schedule: item = (expert, tokenBase, nTok). Output values are
// order-independent -> deterministic.
// =====================================================================
__global__ void bucket_kernel(const int* __restrict__ idx,
                              unsigned short* __restrict__ lists,
                              int* __restrict__ itemE,
                              int* __restrict__ itemB,
                              int* __restrict__ itemN,
                              int* __restrict__ nItems) {
    __shared__ int cnt[NEXP];
    const int t = threadIdx.x;            // 0..511
    if (t < NEXP) cnt[t] = 0;
    __syncthreads();
    const int e = idx[t];
    const int pos = atomicAdd(&cnt[e], 1);
    lists[e * PAIRS + pos] = (unsigned short)t;
    __syncthreads();
    if (t == 0) {
        int n = 0;
        for (int ee = 0; ee < NEXP; ++ee) {
            const int c = cnt[ee];
            for (int b = 0; b < c; b += TT) {
                itemE[n] = ee;
                itemB[n] = b;
                itemN[n] = min(TT, c - b);
                ++n;
            }
        }
        *nItems = n;
    }
}

__device__ __forceinline__ float glu_act(float g, float l) {
    g = fminf(g, LIMIT);
    l = fminf(fmaxf(l, -LIMIT), LIMIT);
    const float sg = 1.0f / (1.0f + __expf(-ALPHA * g));
    return (g * sg) * (l + 1.0f);
}

// pack two f32 -> one dword of 2 bf16 (RNE), lo = first
__device__ __forceinline__ unsigned pack_bf16(float a, float b) {
    unsigned ua = __float_as_uint(a);
    unsigned ub = __float_as_uint(b);
    ua = (ua + 0x7FFFu + ((ua >> 16) & 1u)) >> 16;
    ub = (ub + 0x7FFFu + ((ub >> 16) & 1u)) & 0xFFFF0000u;
    return ua | ub;
}
__device__ __forceinline__ float bflo(unsigned u) { return __uint_as_float(u << 16); }
__device__ __forceinline__ float bfhi(unsigned u) { return __uint_as_float(u & 0xFFFF0000u); }

// =====================================================================
// Kernel 2: block = (c-chunk, work item). 256 threads = 4 waves,
// wave q owns K-quarter [q*128, q*128+128). W is loaded DIRECTLY into
// VGPRs (no LDS round-trip, no barriers, 4-buffer rotating pipeline);
// x is packed bf16 in LDS [k/2][16 tokens]. Thread tile: 4 tok x 4 ch.
// k-split-4 combined through LDS at the end (stride-17, conflict-free).
// =====================================================================
__global__ __launch_bounds__(256, 4) void moe_mlp1_kernel(
    const float* __restrict__ x,      // [128, 512]
    const float* __restrict__ w,      // [32, 1024, 512]
    const float* __restrict__ bias,   // [32, 1024]
    const unsigned short* __restrict__ lists,
    const int* __restrict__ itemE,
    const int* __restrict__ itemB,
    const int* __restrict__ itemN,
    const int* __restrict__ nItems,
    float* __restrict__ out)          // [512, 512] fp32
{
    __shared__ unsigned xs[(KDIM / 2) * TT];   // 256*16 dwords = 16 KB

    const int it = blockIdx.y;
    if (it >= *nItems) return;
    const int e     = itemE[it];
    const int tBase = itemB[it];
    const int nT    = itemN[it];
    const int cBase = blockIdx.x * CH;

    const int tid  = threadIdx.x;
    const int q    = tid >> 6;          // k-quarter = wave id
    const int lane = tid & 63;
    const int cg   = lane & 15;         // channel group -> c0 = cg*4
    const int tg   = lane >> 4;         // token group   -> t0 = tg*4
    const int t0   = tg * 4;

    // two W base pointers so all 16 loads use 13-bit immediate offsets
    const float* wp0 = w + (size_t)(e * CDIM + cBase + cg * 4) * KDIM + q * (KDIM / 4);
    const float* wp2 = wp0 + 2 * KDIM;

    float4 wb[4][4];
#define LOADW(B, S) do {                                   \
        wb[B][0] = *(const float4*)(wp0 + (S) * 4);        \
        wb[B][1] = *(const float4*)(wp0 + KDIM + (S) * 4); \
        wb[B][2] = *(const float4*)(wp2 + (S) * 4);        \
        wb[B][3] = *(const float4*)(wp2 + KDIM + (S) * 4); \
    } while (0)

    // preload 3 steps deep (12 b128 in flight) before x-staging completes
    LOADW(0, 0); LOADW(1, 1); LOADW(2, 2);

    // ---- stage x chunk: packed bf16, layout [k/2][16 tokens] ----
    {
        const int tok  = tid & 15;
        const int kseg = tid >> 4;            // 0..15, 32 k's each
        const bool v   = tok < nT;
        int pair = 0;
        if (v) pair = (int)lists[e * PAIRS + tBase + tok];
        const float4* xr = (const float4*)(x + (size_t)(pair >> 2) * KDIM + kseg * 32);
        #pragma unroll
        for (int r = 0; r < 8; ++r) {
            float4 f = v ? xr[r] : make_float4(0.f, 0.f, 0.f, 0.f);
            const int kp = kseg * 16 + r * 2;
            xs[(kp + 0) * TT + tok] = pack_bf16(f.x, f.y);
            xs[(kp + 1) * TT + tok] = pack_bf16(f.z, f.w);
        }
    }

    float acc[4][4];
    #pragma unroll
    for (int j = 0; j < 4; ++j)
        #pragma unroll
        for (int i = 0; i < 4; ++i) acc[j][i] = 0.f;

#define COMPUTE(B, S) do {                                              \
        const int kp0 = q * 64 + (S) * 2;                               \
        const uint4 xa = *(const uint4*)&xs[(kp0 + 0) * TT + t0];       \
        const uint4 xb = *(const uint4*)&xs[(kp0 + 1) * TT + t0];       \
        const unsigned xd0[4] = {xa.x, xa.y, xa.z, xa.w};               \
        const unsigned xd1[4] = {xb.x, xb.y, xb.z, xb.w};               \
        _Pragma("unroll")                                               \
        for (int j = 0; j < 4; ++j) {                                   \
            const float x0 = bflo(xd0[j]), x1 = bfhi(xd0[j]);           \
            const float x2 = bflo(xd1[j]), x3 = bfhi(xd1[j]);           \
            _Pragma("unroll")                                           \
            for (int i = 0; i < 4; ++i) {                               \
                acc[j][i] = fmaf(x0, wb[B][i].x, acc[j][i]);            \
                acc[j][i] = fmaf(x1, wb[B][i].y, acc[j][i]);            \
                acc[j][i] = fmaf(x2, wb[B][i].z, acc[j][i]);            \
                acc[j][i] = fmaf(x3, wb[B][i].w, acc[j][i]);            \
            }                                                           \
        }                                                               \
    } while (0)

    __syncthreads();   // xs ready

    // ---- barrier-free K-loop, 4-buffer rotating W pipeline (depth 3) ----
    #pragma unroll
    for (int s = 0; s < 32; s += 4) {
        if (s + 3 < 32) LOADW(3, s + 3);
        COMPUTE(0, s);
        if (s + 4 < 32) LOADW(0, s + 4);
        COMPUTE(1, s + 1);
        if (s + 5 < 32) LOADW(1, s + 5);
        COMPUTE(2, s + 2);
        if (s + 6 < 32) LOADW(2, s + 6);
        COMPUTE(3, s + 3);
    }

    // ---- 4-way k-split combine through LDS (stride-17: conflict-free) ----
    __syncthreads();
    float* ov = (float*)xs;
    if (q != 0) {
        const int base = ((q - 1) * 64 + lane) * 17;
        #pragma unroll
        for (int j = 0; j < 4; ++j)
            #pragma unroll
            for (int i = 0; i < 4; ++i) ov[base + j * 4 + i] = acc[j][i];
    }
    __syncthreads();
    if (q == 0) {
        #pragma unroll
        for (int r = 0; r < 3; ++r) {
            const int base = (r * 64 + lane) * 17;
            #pragma unroll
            for (int j = 0; j < 4; ++j)
                #pragma unroll
                for (int i = 0; i < 4; ++i) acc[j][i] += ov[base + j * 4 + i];
        }
        const float4 bv = *(const float4*)(bias + (size_t)e * CDIM + cBase + cg * 4);
        #pragma unroll
        for (int j = 0; j < 4; ++j) {
            const int tl = t0 + j;
            if (tl < nT) {
                const int pair = (int)lists[e * PAIRS + tBase + tl];
                const float g0 = acc[j][0] + bv.x, l0 = acc[j][1] + bv.y;
                const float g1 = acc[j][2] + bv.z, l1 = acc[j][3] + bv.w;
                float2 o;
                o.x = glu_act(g0, l0);
                o.y = glu_act(g1, l1);
                *(float2*)&out[(size_t)pair * HALF_C + (cBase >> 1) + cg * 2] = o;
            }
        }
    }
#undef LOADW
#undef COMPUTE
}

extern "C" void kernel_launch(void* const* d_in, const int* in_sizes, int n_in,
                              void* d_out, int out_size, void* d_ws, size_t ws_size,
                              hipStream_t stream) {
    const float* x    = (const float*)d_in[0];
    const int*   idx  = (const int*)d_in[1];
    const float* w    = (const float*)d_in[2];
    const float* bias = (const float*)d_in[3];
    float* out = (float*)d_out;

    char* wsb = (char*)d_ws;
    unsigned short* lists = (unsigned short*)wsb;                 // 32 KB
    int* itemE  = (int*)(wsb + 32768);
    int* itemB  = (int*)(wsb + 32768 + MAXIT * 4);
    int* itemN  = (int*)(wsb + 32768 + MAXIT * 8);
    int* nItems = (int*)(wsb + 32768 + MAXIT * 12);

    bucket_kernel<<<1, PAIRS, 0, stream>>>(idx, lists, itemE, itemB, itemN, nItems);

    dim3 grid(CDIM / CH, MAXIT);   // (16, 64)
    moe_mlp1_kernel<<<grid, 256, 0, stream>>>(x, w, bias, lists,
                                              itemE, itemB, itemN, nItems, out);
}

// Round 4
// 34.452 us; speedup vs baseline: 1.8283x; 1.8283x over previous
//
#include <hip/hip_runtime.h>

// ---- problem constants ----
#define B_TOK   128
#define E_TOP   4
#define NEXP    32
#define KDIM    512
#define CDIM    1024
#define PAIRS   (B_TOK * E_TOP)   // 512
#define HALF_C  (CDIM / 2)        // 512

#define ALPHA   1.702f
#define LIMIT   7.0f

#define TT      16                // tokens per work item (MFMA N)
#define MAXIT   64                // Σceil(Te/16) ≤ 64

typedef __attribute__((ext_vector_type(8))) short short8;   // bf16x8 frag
typedef __attribute__((ext_vector_type(4))) float f32x4;    // fp32 acc

// =====================================================================
// Kernel 1: bucket (b,e) pairs by expert and build work items.
// Output values are order-independent -> deterministic.
// =====================================================================
__global__ void bucket_kernel(const int* __restrict__ idx,
                              unsigned short* __restrict__ lists,
                              int* __restrict__ itemE,
                              int* __restrict__ itemB,
                              int* __restrict__ itemN,
                              int* __restrict__ nItems) {
    __shared__ int cnt[NEXP];
    const int t = threadIdx.x;            // 0..511
    if (t < NEXP) cnt[t] = 0;
    __syncthreads();
    const int e = idx[t];
    const int pos = atomicAdd(&cnt[e], 1);
    lists[e * PAIRS + pos] = (unsigned short)t;
    __syncthreads();
    if (t == 0) {
        int n = 0;
        for (int ee = 0; ee < NEXP; ++ee) {
            const int c = cnt[ee];
            for (int b = 0; b < c; b += TT) {
                itemE[n] = ee;
                itemB[n] = b;
                itemN[n] = min(TT, c - b);
                ++n;
            }
        }
        *nItems = n;
    }
}

__device__ __forceinline__ float glu_act(float g, float l) {
    g = fminf(g, LIMIT);
    l = fminf(fmaxf(l, -LIMIT), LIMIT);
    const float sg = 1.0f / (1.0f + __expf(-ALPHA * g));
    return (g * sg) * (l + 1.0f);
}

// two f32 -> one dword holding 2 bf16 (RNE); lo = a, hi = b
__device__ __forceinline__ unsigned pack_bf16(float a, float b) {
    unsigned ua = __float_as_uint(a);
    unsigned ub = __float_as_uint(b);
    ua = (ua + 0x7FFFu + ((ua >> 16) & 1u)) >> 16;
    ub = (ub + 0x7FFFu + ((ub >> 16) & 1u)) & 0xFFFF0000u;
    return ua | ub;
}

// 8 f32 (two float4, k-ascending) -> bf16x8 fragment
__device__ __forceinline__ short8 cvt8(float4 lo, float4 hi) {
    union { unsigned u[4]; short8 s; } r;
    r.u[0] = pack_bf16(lo.x, lo.y);
    r.u[1] = pack_bf16(lo.z, lo.w);
    r.u[2] = pack_bf16(hi.x, hi.y);
    r.u[3] = pack_bf16(hi.z, hi.w);
    return r.s;
}

#define LDF4(p, off) (*(const float4*)((p) + (off)))

// =====================================================================
// Kernel 2: block = (64-ch chunk, work item); 4 waves, each wave owns a
// 16-channel MFMA tile over full K (16 steps of 16x16x32 bf16).
//   A = W tile  : lane holds ch = base + (lane&15), k = kg*8..kg*8+7
//   B = x tile  : lane holds tok = lane&15,         k = kg*8..kg*8+7
//   C/D         : lane holds token = lane&15, channels (lane>>4)*4+reg
// No LDS, no barriers, no k-split. fp32 accumulation in AGPR/VGPR.
// =====================================================================
__global__ __launch_bounds__(256, 4) void moe_mlp1_kernel(
    const float* __restrict__ x,      // [128, 512]
    const float* __restrict__ w,      // [32, 1024, 512]
    const float* __restrict__ bias,   // [32, 1024]
    const unsigned short* __restrict__ lists,
    const int* __restrict__ itemE,
    const int* __restrict__ itemB,
    const int* __restrict__ itemN,
    const int* __restrict__ nItems,
    float* __restrict__ out)          // [512, 512] fp32
{
    const int it = blockIdx.y;
    if (it >= *nItems) return;
    const int e     = itemE[it];
    const int tBase = itemB[it];
    const int nT    = itemN[it];

    const int wave = threadIdx.x >> 6;
    const int lane = threadIdx.x & 63;
    const int kg   = lane >> 4;                         // k-group 0..3
    const int tok  = lane & 15;

    const int chA = blockIdx.x * 64 + wave * 16 + (lane & 15);  // A-row channel

    // token pair index for this lane's B-column (guard: lists beyond count
    // is uninitialized ws memory -> clamp to 0, result discarded at store)
    const int pr = (tok < nT) ? (int)lists[e * PAIRS + tBase + tok] : 0;

    const float* wp = w + ((size_t)e * CDIM + chA) * KDIM + kg * 8;
    const float* xp = x + (size_t)(pr >> 2) * KDIM + kg * 8;

    f32x4 acc = {0.f, 0.f, 0.f, 0.f};

    // fully-unrolled 16-step K loop; depth-1 explicit prefetch, compiler
    // free to deepen within the 128-VGPR budget (launch_bounds 256,4).
    float4 w0 = LDF4(wp, 0), w1 = LDF4(wp, 4);
    float4 x0 = LDF4(xp, 0), x1 = LDF4(xp, 4);
    #pragma unroll
    for (int s = 0; s < 16; ++s) {
        float4 nw0, nw1, nx0, nx1;
        if (s + 1 < 16) {
            const int o = (s + 1) * 32;
            nw0 = LDF4(wp, o); nw1 = LDF4(wp, o + 4);
            nx0 = LDF4(xp, o); nx1 = LDF4(xp, o + 4);
        }
        acc = __builtin_amdgcn_mfma_f32_16x16x32_bf16(
                  cvt8(w0, w1), cvt8(x0, x1), acc, 0, 0, 0);
        w0 = nw0; w1 = nw1; x0 = nx0; x1 = nx1;
    }

    // ---- epilogue: bias + interleaved GLU, lane-local ----
    // lane holds channels cb..cb+3 (cb % 4 == 0) for token `tok`
    const int cb = blockIdx.x * 64 + wave * 16 + kg * 4;
    const float4 bv = *(const float4*)(bias + (size_t)e * CDIM + cb);
    if (tok < nT) {
        const float g0 = acc[0] + bv.x, l0 = acc[1] + bv.y;
        const float g1 = acc[2] + bv.z, l1 = acc[3] + bv.w;
        float2 o;
        o.x = glu_act(g0, l0);
        o.y = glu_act(g1, l1);
        *(float2*)&out[(size_t)pr * HALF_C + (cb >> 1)] = o;
    }
}

extern "C" void kernel_launch(void* const* d_in, const int* in_sizes, int n_in,
                              void* d_out, int out_size, void* d_ws, size_t ws_size,
                              hipStream_t stream) {
    const float* x    = (const float*)d_in[0];
    const int*   idx  = (const int*)d_in[1];
    const float* w    = (const float*)d_in[2];
    const float* bias = (const float*)d_in[3];
    float* out = (float*)d_out;

    char* wsb = (char*)d_ws;
    unsigned short* lists = (unsigned short*)wsb;                 // 32 KB
    int* itemE  = (int*)(wsb + 32768);
    int* itemB  = (int*)(wsb + 32768 + MAXIT * 4);
    int* itemN  = (int*)(wsb + 32768 + MAXIT * 8);
    int* nItems = (int*)(wsb + 32768 + MAXIT * 12);

    bucket_kernel<<<1, PAIRS, 0, stream>>>(idx, lists, itemE, itemB, itemN, nItems);

    dim3 grid(CDIM / 64, MAXIT);   // (16, 64) blocks, 4 waves each
    moe_mlp1_kernel<<<grid, 256, 0, stream>>>(x, w, bias, lists,
                                              itemE, itemB, itemN, nItems, out);
}

// Round 5
// 27.708 us; speedup vs baseline: 2.2733x; 1.2434x over previous
//
#include <hip/hip_runtime.h>
#include <hip/hip_bf16.h>

// ---- problem constants ----
#define B_TOK   128
#define E_TOP   4
#define NEXP    32
#define KDIM    512
#define CDIM    1024
#define PAIRS   (B_TOK * E_TOP)   // 512
#define HALF_C  (CDIM / 2)        // 512

#define ALPHA   1.702f
#define LIMIT   7.0f

#define TT      32                // tokens per item -> 1 item/expert (usually)
#define MAXIT   48

typedef __attribute__((ext_vector_type(8))) short short8;   // bf16x8 frag
typedef __attribute__((ext_vector_type(4))) float f32x4;

// =====================================================================
// Kernel 1: bucket (b,e) pairs by expert, build TT=32 work items.
// Output values order-independent -> deterministic.
// =====================================================================
__global__ void bucket_kernel(const int* __restrict__ idx,
                              unsigned short* __restrict__ lists,
                              int* __restrict__ itemE,
                              int* __restrict__ itemB,
                              int* __restrict__ itemN,
                              int* __restrict__ nItems) {
    __shared__ int cnt[NEXP];
    const int t = threadIdx.x;            // 0..511
    if (t < NEXP) cnt[t] = 0;
    __syncthreads();
    const int e = idx[t];
    const int pos = atomicAdd(&cnt[e], 1);
    lists[e * PAIRS + pos] = (unsigned short)t;
    __syncthreads();
    if (t == 0) {
        int n = 0;
        for (int ee = 0; ee < NEXP; ++ee) {
            const int c = cnt[ee];
            for (int b = 0; b < c; b += TT) {
                itemE[n] = ee;
                itemB[n] = b;
                itemN[n] = min(TT, c - b);
                ++n;
            }
        }
        *nItems = n;
    }
}

__device__ __forceinline__ float glu_act(float g, float l) {
    g = fminf(g, LIMIT);
    l = fminf(fmaxf(l, -LIMIT), LIMIT);
    const float sg = 1.0f / (1.0f + __expf(-ALPHA * g));
    return (g * sg) * (l + 1.0f);
}

// two f32 -> dword of 2 bf16 (RNE), lo = a
__device__ __forceinline__ unsigned pk2(float a, float b) {
    union { __hip_bfloat16 h; unsigned short u; } ca, cb;
    ca.h = __float2bfloat16(a);
    cb.h = __float2bfloat16(b);
    return (unsigned)ca.u | ((unsigned)cb.u << 16);
}

// 8 f32 (k-ascending) -> bf16x8 fragment
__device__ __forceinline__ short8 cvt8(float4 lo, float4 hi) {
    union { unsigned u[4]; short8 s; } r;
    r.u[0] = pk2(lo.x, lo.y);
    r.u[1] = pk2(lo.z, lo.w);
    r.u[2] = pk2(hi.x, hi.y);
    r.u[3] = pk2(hi.z, hi.w);
    return r.s;
}

#define LDF4(p, off) (*(const float4*)((p) + (off)))

// =====================================================================
// Kernel 2: block = (32-ch chunk, expert item). 4 waves = 2 k-halves x
// 2 ch-groups. Wave (kh,cs): channels cBase+cs*16+(lane&15), K-half kh,
// 8 MFMA steps x 2 MFMAs (tokens 0-15 / 16-31) sharing the A(W) frag.
//  - W: global->VGPR depth-3 ring, issued BEFORE x staging (lat hidden)
//  - x: staged ONCE to LDS as bf16 in frag-linear layout:
//       frag(sglob, half) at byte (sglob*2+half)*1024 + lane*16
//       -> ds_read_b128 at stride 16B/lane = conflict-free, no per-step
//       global x traffic at all.
//  - k-combine 2-way via small LDS buffer; GLU epilogue lane-local.
// W is streamed from HBM exactly once (64 MB total).
// =====================================================================
__global__ __launch_bounds__(256, 4) void moe_mlp1_kernel(
    const float* __restrict__ x,      // [128, 512]
    const float* __restrict__ w,      // [32, 1024, 512]
    const float* __restrict__ bias,   // [32, 1024]
    const unsigned short* __restrict__ lists,
    const int* __restrict__ itemE,
    const int* __restrict__ itemB,
    const int* __restrict__ itemN,
    const int* __restrict__ nItems,
    float* __restrict__ out)          // [512, 512] fp32
{
    __shared__ char  xbl[TT * KDIM * 2];   // 32 KB bf16 frag-linear
    __shared__ float red[2][64][8];        // 4 KB k-combine

    const int it = blockIdx.y;
    if (it >= *nItems) return;
    const int e     = itemE[it];
    const int tBase = itemB[it];
    const int nT    = itemN[it];
    const int cBase = blockIdx.x * 32;

    const int tid  = threadIdx.x;
    const int wv   = tid >> 6;
    const int lane = tid & 63;
    const int kh   = wv >> 1;          // k-half
    const int cs   = wv & 1;           // channel sub-group
    const int kg   = lane >> 4;        // k-group within MFMA step
    const int c16  = lane & 15;

    const int chA = cBase + cs * 16 + c16;
    const float* wp = w + ((size_t)e * CDIM + chA) * KDIM + kh * 256 + kg * 8;

    // ---- W prefetch ring, issued first so HBM latency hides under stage ----
    constexpr int D = 3;
    float4 w0[D], w1[D];
    #pragma unroll
    for (int p = 0; p < D; ++p) {
        w0[p] = LDF4(wp, p * 32);
        w1[p] = LDF4(wp, p * 32 + 4);
    }

    // ---- stage x -> LDS bf16, frag-linear ----
    // unit uu in [0,512): token t = uu&31, step s = uu>>5 (32 k's)
    #pragma unroll
    for (int rep = 0; rep < 2; ++rep) {
        const int uu = tid + rep * 256;
        const int t  = uu & 31;
        const int s  = uu >> 5;
        const int pr = (t < nT) ? (int)lists[e * PAIRS + tBase + t] : 0;
        const float* xr = x + (size_t)(pr >> 2) * KDIM + s * 32;
        char* dst = &xbl[(s * 2 + (t >> 4)) * 1024 + (t & 15) * 16];
        #pragma unroll
        for (int g = 0; g < 4; ++g) {
            const float4 lo = LDF4(xr, g * 8);
            const float4 hi = LDF4(xr, g * 8 + 4);
            *(short8*)(dst + g * 256) = cvt8(lo, hi);
        }
    }
    __syncthreads();

    // ---- barrier-free K-loop: 8 steps, 2 MFMAs/step ----
    f32x4 acc0 = {0.f, 0.f, 0.f, 0.f};
    f32x4 acc1 = {0.f, 0.f, 0.f, 0.f};
    const char* xb = &xbl[(kh * 8) * 2048 + lane * 16];
    #pragma unroll
    for (int s = 0; s < 8; ++s) {
        const short8 a = cvt8(w0[s % D], w1[s % D]);
        if (s + D < 8) {
            w0[s % D] = LDF4(wp, (s + D) * 32);
            w1[s % D] = LDF4(wp, (s + D) * 32 + 4);
        }
        const short8 b0 = *(const short8*)(xb + s * 2048);
        const short8 b1 = *(const short8*)(xb + s * 2048 + 1024);
        acc0 = __builtin_amdgcn_mfma_f32_16x16x32_bf16(a, b0, acc0, 0, 0, 0);
        acc1 = __builtin_amdgcn_mfma_f32_16x16x32_bf16(a, b1, acc1, 0, 0, 0);
    }

    // ---- 2-way k-combine + epilogue ----
    if (kh == 1) {
        #pragma unroll
        for (int i = 0; i < 4; ++i) {
            red[cs][lane][i]     = acc0[i];
            red[cs][lane][4 + i] = acc1[i];
        }
    }
    __syncthreads();
    if (kh == 0) {
        #pragma unroll
        for (int i = 0; i < 4; ++i) {
            acc0[i] += red[cs][lane][i];
            acc1[i] += red[cs][lane][4 + i];
        }
        // D-lane: token = lane&15 (acc0) / +16 (acc1), channels cb..cb+3
        const int cb = cBase + cs * 16 + kg * 4;
        const float4 bv = *(const float4*)(bias + (size_t)e * CDIM + cb);
        const int tA = lane & 15;
        if (tA < nT) {
            const int pr = (int)lists[e * PAIRS + tBase + tA];
            float2 o;
            o.x = glu_act(acc0[0] + bv.x, acc0[1] + bv.y);
            o.y = glu_act(acc0[2] + bv.z, acc0[3] + bv.w);
            *(float2*)&out[(size_t)pr * HALF_C + (cb >> 1)] = o;
        }
        if (tA + 16 < nT) {
            const int pr = (int)lists[e * PAIRS + tBase + tA + 16];
            float2 o;
            o.x = glu_act(acc1[0] + bv.x, acc1[1] + bv.y);
            o.y = glu_act(acc1[2] + bv.z, acc1[3] + bv.w);
            *(float2*)&out[(size_t)pr * HALF_C + (cb >> 1)] = o;
        }
    }
}

extern "C" void kernel_launch(void* const* d_in, const int* in_sizes, int n_in,
                              void* d_out, int out_size, void* d_ws, size_t ws_size,
                              hipStream_t stream) {
    const float* x    = (const float*)d_in[0];
    const int*   idx  = (const int*)d_in[1];
    const float* w    = (const float*)d_in[2];
    const float* bias = (const float*)d_in[3];
    float* out = (float*)d_out;

    char* wsb = (char*)d_ws;
    unsigned short* lists = (unsigned short*)wsb;                 // 32 KB
    int* itemE  = (int*)(wsb + 32768);
    int* itemB  = (int*)(wsb + 32768 + MAXIT * 4);
    int* itemN  = (int*)(wsb + 32768 + MAXIT * 8);
    int* nItems = (int*)(wsb + 32768 + MAXIT * 12);

    bucket_kernel<<<1, PAIRS, 0, stream>>>(idx, lists, itemE, itemB, itemN, nItems);

    dim3 grid(CDIM / 32, MAXIT);   // (32, 48); ~1024 active blocks = 4/CU
    moe_mlp1_kernel<<<grid, 256, 0, stream>>>(x, w, bias, lists,
                                              itemE, itemB, itemN, nItems, out);
}